// Round 11
// baseline (101.028 us; speedup 1.0000x reference)
//
#include <hip/hip_runtime.h>
#include <hip/hip_bf16.h>
#include <math.h>

#define UQ   1024
#define NUQ  2048
#define MQ   64
#define NN   2112
#define HD   256

typedef __attribute__((ext_vector_type(4))) float f32x4;
typedef __attribute__((ext_vector_type(8))) __bf16 bf16x8;

// ---- workspace layout (bytes) ----
#define OFF_HB    0u          // UAV h f32 [64][256]                65,536
#define OFF_HUF   65536u      // h frag bf16 [33][8][4][512]     1,081,344
#define OFF_PUBF  1146880u    // P_user frag bf16 [8][8][16][512]1,048,576
#define OFF_PB    2195456u    // P_uav+b1 f32 [64][256]             65,536
#define OFF_SPR   2260992u    // s'_m f32 [64]                         256
#define OFF_ATT   2261248u    // wqa[256], v[256], const0            2,304
#define OFF_WHHT  2263552u    // user WhhT2 f32 [2][128][512]      524,288
#define OFF_WIHT  2787840u    // uav WihT2 f32 [2][256][512]     1,048,576
#define OFF_W1F   3836416u    // msg_w1 frag bf16 [16][16][512]    262,144
#define OFF_W2F   4098560u    // msg_w2 frag bf16 [8][16][512]     131,072
#define OFF_UW1F  4229632u    // upd_w1 frag bf16 [16][16][512]    262,144
#define OFF_UW2F  4491776u    // upd_w2 frag bf16 [8][16][512]     131,072
#define OFF_CREC  4622848u    // chunk rec f32 [512][260]          532,480
#define OFF_H2U   5155328u    // h2 UAV f32 [64][256]               65,536
#define OFF_PART  5220864u    // uav-lstm gate partials [64][4][1024] f32 1,048,576
// total ~6.3 MB

__device__ __forceinline__ float sigm(float v) { return 1.f / (1.f + expf(-v)); }

// fragment-major index helpers: element (row, k)
__device__ __forceinline__ int huf_idx(int row, int k) {   // [33][8][4][512]
  return (((row >> 6) * 8 + (k >> 5)) * 4 + ((row >> 4) & 3)) * 512 +
         (((k >> 3) & 3) * 16 + (row & 15)) * 8 + (k & 7);
}
__device__ __forceinline__ int pubf_idx(int row, int k) {  // [8][8][16][512]
  return (((row >> 8) * 8 + (k >> 5)) * 16 + ((row >> 4) & 15)) * 512 +
         (((k >> 3) & 3) * 16 + (row & 15)) * 8 + (k & 7);
}

__device__ __forceinline__ void gl16(const void* g, void* l) {
  __builtin_amdgcn_global_load_lds((const __attribute__((address_space(1))) void*)g,
                                   (__attribute__((address_space(3))) void*)l, 16, 0, 0);
}

// =====================================================================
// K0: weight preprocessing — LDS-tiled transposes + fragment-major casts
// =====================================================================
__device__ void tile_transpose_perm(const float* __restrict__ in, int in_ld,
                                    float* __restrict__ out, int out_ld,
                                    int k0, int c0) {
  __shared__ float ldt[64][68];
  const int t = threadIdx.x;
  {
    const int ci = t >> 2, kq = t & 3;
    const int c = c0 + ci;
    const int row = (c & 3) * 128 + (c >> 2);
    const float* src = in + row * in_ld + k0 + kq * 16;
#pragma unroll
    for (int e = 0; e < 4; ++e)
      *(f32x4*)&ldt[ci][kq * 16 + e * 4] = *(const f32x4*)(src + e * 4);
  }
  __syncthreads();
  {
    const int kk = t >> 2, cq = t & 3;
    float* dst = out + (k0 + kk) * out_ld + c0 + cq * 16;
#pragma unroll
    for (int e4 = 0; e4 < 4; ++e4) {
      f32x4 v;
#pragma unroll
      for (int j = 0; j < 4; ++j) v[j] = ldt[cq * 16 + e4 * 4 + j][kk];
      *(f32x4*)(dst + e4 * 4) = v;
    }
  }
}

template<int K>
__device__ void frag_cast16(const float* __restrict__ W, int j0, __bf16* __restrict__ frag) {
  __shared__ float ldc[16][K + 4];
  const int t = threadIdx.x;
  {
    const int jr = t >> 4, kq = t & 15;
    const float* src = W + (j0 + jr) * K + kq * (K / 16);
#pragma unroll
    for (int e = 0; e < K / 64; ++e)
      *(f32x4*)&ldc[jr][kq * (K / 16) + e * 4] = *(const f32x4*)(src + e * 4);
  }
  __syncthreads();
  const int f = j0 >> 4;
  constexpr int nks = K >> 5;
  constexpr int thr_per_ks = 256 / nks;
  constexpr int q_per_thr = 512 / thr_per_ks;
  const int ks = t / thr_per_ks;
  const int q0 = (t % thr_per_ks) * q_per_thr;
#pragma unroll
  for (int h = 0; h < q_per_thr / 8; ++h) {
    bf16x8 v;
#pragma unroll
    for (int e = 0; e < 8; ++e) {
      int q = q0 + h * 8 + e;
      int lane = q >> 3;
      v[e] = (__bf16)ldc[lane & 15][ks * 32 + (lane >> 4) * 8 + (q & 7)];
    }
    *(bf16x8*)(frag + (ks * 16 + f) * 512 + q0 + h * 8) = v;
  }
}

__global__ __launch_bounds__(256) void k0_prep(
    const float* __restrict__ ul_whh, const float* __restrict__ uavl_wih,
    const float* __restrict__ msg_w1, const float* __restrict__ msg_w2,
    const float* __restrict__ upd_w1, const float* __restrict__ upd_w2,
    const float* __restrict__ att_w,  const float* __restrict__ att_b,
    const float* __restrict__ wq_w,   const float* __restrict__ wq_b,
    const float* __restrict__ wr_w,   const float* __restrict__ wr_b,
    char* __restrict__ ws)
{
  const int b = blockIdx.x, t = threadIdx.x;
  if (b < 32) {
    const int dir = b >> 4, tile = b & 15;
    tile_transpose_perm(ul_whh + dir * 65536, 128,
                        (float*)(ws + OFF_WHHT) + dir * 65536, 512,
                        (tile >> 3) * 64, (tile & 7) * 64);
  } else if (b < 96) {
    const int b2 = b - 32, dir = b2 >> 5, tile = b2 & 31;
    tile_transpose_perm(uavl_wih + dir * 131072, 256,
                        (float*)(ws + OFF_WIHT) + dir * 131072, 512,
                        (tile >> 3) * 64, (tile & 7) * 64);
  } else if (b < 112) {
    frag_cast16<256>(msg_w2, (b - 96) * 16, (__bf16*)(ws + OFF_W2F));
  } else if (b < 128) {
    frag_cast16<512>(msg_w1, (b - 112) * 16, (__bf16*)(ws + OFF_W1F));
  } else if (b < 144) {
    frag_cast16<512>(upd_w1, (b - 128) * 16, (__bf16*)(ws + OFF_UW1F));
  } else if (b < 160) {
    frag_cast16<256>(upd_w2, (b - 144) * 16, (__bf16*)(ws + OFF_UW2F));
  } else {
    float* wqa = (float*)(ws + OFF_ATT);
    float* vv  = wqa + 256;
    float* c0  = wqa + 512;
    float sa = 0.f, sr = 0.f;
    for (int j = 0; j < 256; ++j) {
      sa += att_w[j]       * wq_w[j * 256 + t];
      sr += att_w[256 + j] * wr_w[j * 256 + t];
    }
    wqa[t] = sa; vv[t] = sr;
    __shared__ float red[256];
    red[t] = att_w[t] * wq_b[t] + att_w[256 + t] * wr_b[t];
    __syncthreads();
    for (int s = 128; s > 0; s >>= 1) { if (t < s) red[t] += red[t + s]; __syncthreads(); }
    if (t == 0) c0[0] = red[0] + att_b[0];
  }
}

// =====================================================================
// K1: user BiLSTM (4 users/block, coalesced frag stores) + UAV embed
// =====================================================================
__global__ __launch_bounds__(256) void k1_embed(
    const float* __restrict__ x, const float* __restrict__ ul_wih,
    const float* __restrict__ ul_b, const float* __restrict__ uav_lin_w,
    const float* __restrict__ uav_lin_b, char* __restrict__ ws)
{
  __bf16* huf = (__bf16*)(ws + OFF_HUF);
  const int b = blockIdx.x, tid = threadIdx.x;
  if (b < 256) {
    const float* whhT = (const float*)(ws + OFF_WHHT);
    const int dir = tid >> 7, hc = tid & 127;
    const int u0 = b * 4;
    float wx[4], wy[4], bb[4];
#pragma unroll
    for (int g = 0; g < 4; ++g) {
      int row = g * 128 + hc;
      wx[g] = ul_wih[dir * 1024 + row * 2 + 0];
      wy[g] = ul_wih[dir * 1024 + row * 2 + 1];
      bb[g] = ul_b[dir * 512 + row];
    }
    __shared__ float h1s[2][128][4];
    __shared__ float hout[8][260];
    float c1[4], h1v[4], in1x[4], in1y[4];
#pragma unroll
    for (int uu = 0; uu < 4; ++uu) {
      int u = u0 + uu;
      float ax = x[u * 2], ay = x[u * 2 + 1];
      float bx = x[(UQ + u) * 2], by = x[(UQ + u) * 2 + 1];
      float i0x = dir ? bx : ax, i0y = dir ? by : ay;
      in1x[uu] = dir ? ax : bx; in1y[uu] = dir ? ay : by;
      float gv[4];
#pragma unroll
      for (int g = 0; g < 4; ++g) gv[g] = wx[g] * i0x + wy[g] * i0y + bb[g];
      float ii = sigm(gv[0]), gg = tanhf(gv[2]), oo = sigm(gv[3]);
      c1[uu] = ii * gg;
      h1v[uu] = oo * tanhf(c1[uu]);
      h1s[dir][hc][uu] = h1v[uu];
    }
    __syncthreads();
    float acc[4][4];
#pragma unroll
    for (int uu = 0; uu < 4; ++uu)
#pragma unroll
      for (int g = 0; g < 4; ++g) acc[uu][g] = wx[g] * in1x[uu] + wy[g] * in1y[uu] + bb[g];
#pragma unroll 4
    for (int k = 0; k < 128; ++k) {
      f32x4 hv  = *(const f32x4*)&h1s[dir][k][0];
      f32x4 wv4 = *(const f32x4*)(whhT + dir * 65536 + k * 512 + hc * 4);
#pragma unroll
      for (int uu = 0; uu < 4; ++uu)
#pragma unroll
        for (int g = 0; g < 4; ++g) acc[uu][g] += hv[uu] * wv4[g];
    }
    const int col = dir * 128 + hc;
#pragma unroll
    for (int uu = 0; uu < 4; ++uu) {
      float ii = sigm(acc[uu][0]), ff = sigm(acc[uu][1]);
      float gg = tanhf(acc[uu][2]), oo = sigm(acc[uu][3]);
      float c2 = ff * c1[uu] + ii * gg;
      float h2v = oo * tanhf(c2);
      float va = dir ? h2v : h1v[uu];   // node u
      float vb = dir ? h1v[uu] : h2v;   // node UQ+u
      hout[uu][col] = va;
      hout[4 + uu][col] = vb;
    }
    __syncthreads();
    {
      const int lr = tid >> 5, c = tid & 31;
      bf16x8 v;
#pragma unroll
      for (int e = 0; e < 8; ++e) v[e] = (__bf16)hout[lr][c * 8 + e];
      const int node = (lr < 4) ? (u0 + lr) : (UQ + u0 + lr - 4);
      *(bf16x8*)(huf + huf_idx(node, c * 8)) = v;
    }
  } else {
    float* hb = (float*)(ws + OFF_HB);
    const int j = tid;
    const int mb = (b - 256) * 16;
    for (int m = mb; m < mb + 16; ++m) {
      float xa = x[(NUQ + m) * 2], xb = x[(NUQ + m) * 2 + 1];
      float val = xa * uav_lin_w[j * 2] + xb * uav_lin_w[j * 2 + 1] + uav_lin_b[j];
      hb[m * 256 + j] = val;
      huf[huf_idx(NUQ + m, j)] = (__bf16)val;
    }
  }
}

// =====================================================================
// frag-major MFMA GEMM core: 4 waves (cg over 64-col groups), G*16 rows
// =====================================================================
template<int G, int NKS>
__device__ __forceinline__ void frag_gemm_acc_g(const __bf16* __restrict__ Abase, int g0,
                                                const __bf16* __restrict__ Bbase,
                                                f32x4 acc[G][4]) {
  const int lane = threadIdx.x & 63;
  const int cg = (threadIdx.x >> 6) & 3;
  for (int ks = 0; ks < NKS; ++ks) {
    bf16x8 Af[G], Bf[4];
#pragma unroll
    for (int g = 0; g < G; ++g)
      Af[g] = *(const bf16x8*)(Abase + ((ks * 4 + g0 + g) * 64 + lane) * 8);
#pragma unroll
    for (int f = 0; f < 4; ++f)
      Bf[f] = *(const bf16x8*)(Bbase + ((ks * 16 + cg * 4 + f) * 64 + lane) * 8);
#pragma unroll
    for (int g = 0; g < G; ++g)
#pragma unroll
      for (int f = 0; f < 4; ++f)
        acc[g][f] = __builtin_amdgcn_mfma_f32_16x16x32_bf16(Af[g], Bf[f], acc[g][f], 0, 0, 0);
  }
}

// =====================================================================
// K2: P_user frag (64 x 32-row blocks, LDS-coalesced stores),
//     P_uav+b1 (1), s'_m (1)
// =====================================================================
__global__ __launch_bounds__(256) void k2_proj(const float* __restrict__ msg_b1,
                                               char* __restrict__ ws)
{
  const __bf16* huf = (const __bf16*)(ws + OFF_HUF);
  const __bf16* w1f = (const __bf16*)(ws + OFF_W1F);
  const int b = blockIdx.x;
  const int tid = threadIdx.x;
  const int lane = tid & 63, cg = tid >> 6;
  const int cl = lane & 15, g16 = lane >> 4;
  if (b < 64) {
    f32x4 acc[2][4] = {};
    frag_gemm_acc_g<2, 8>(huf + (b >> 1) * 16384, (b & 1) * 2, w1f + 65536, acc);
    __shared__ float ldt[32][264];
#pragma unroll
    for (int g = 0; g < 2; ++g)
#pragma unroll
      for (int f = 0; f < 4; ++f)
#pragma unroll
        for (int r = 0; r < 4; ++r)
          ldt[g * 16 + g16 * 4 + r][cg * 64 + f * 16 + cl] = acc[g][f][r];
    __syncthreads();
    __bf16* pubf = (__bf16*)(ws + OFF_PUBF);
    const int c2 = b >> 3, r16base = (b & 7) * 2;
#pragma unroll
    for (int p = 0; p < 4; ++p) {
      const int region = p * 4 + (tid >> 6);       // 0..15
      const int ks = region >> 1, r16l = region & 1;
      const int row15 = tid & 15, kg = (tid >> 4) & 3;
      const int row = r16l * 16 + row15;
      bf16x8 v;
#pragma unroll
      for (int j = 0; j < 8; ++j) v[j] = (__bf16)ldt[row][ks * 32 + kg * 8 + j];
      const int dst = ((c2 * 8 + ks) * 16 + (r16base + r16l)) * 512 + (kg * 16 + row15) * 8;
      *(bf16x8*)(pubf + dst) = v;
    }
  } else if (b == 64) {
    f32x4 acc[4][4] = {};
    frag_gemm_acc_g<4, 8>(huf + 32 * 16384, 0, w1f, acc);
    float* pb = (float*)(ws + OFF_PB);
#pragma unroll
    for (int g = 0; g < 4; ++g)
#pragma unroll
      for (int f = 0; f < 4; ++f)
#pragma unroll
        for (int r = 0; r < 4; ++r) {
          int row = g * 16 + g16 * 4 + r;
          int col = cg * 64 + f * 16 + cl;
          pb[row * 256 + col] = acc[g][f][r] + msg_b1[col];
        }
  } else {
    const float* hb  = (const float*)(ws + OFF_HB);
    const float* wqa = (const float*)(ws + OFF_ATT);
    const float* c0  = wqa + 512;
    float* spr = (float*)(ws + OFF_SPR);
    if (tid < 64) {
      float s = 0.f;
      for (int k = 0; k < 256; ++k) s += hb[tid * 256 + k] * wqa[k];
      spr[tid] = s + c0[0];
    }
  }
}

// =====================================================================
// K3': blocks 0..511 = edge msg layer-2 + attention + chunk softmax
// (exact R4 structure: 16 waves, rot, setprio, gl16-dbuf B, staged A
// repack). Blocks 512..575 = k56-USER rows (independent of k3 output;
// scheduled last -> run in k3's drain shadow). LDS aliased onto bufA/B.
// =====================================================================
__global__ __launch_bounds__(1024, 2) void k3_edge(
    const float* __restrict__ msg_b2,
    const float* __restrict__ upd_b1, const float* __restrict__ upd_b2,
    const float* __restrict__ lin2_w, const float* __restrict__ lin2_b,
    float* __restrict__ out, char* __restrict__ ws)
{
  __shared__ __align__(16) char bufA[2][16384];
  __shared__ __align__(16) char bufB[2][16384];
  __shared__ float plds[16][64];
  __shared__ float redmax[16], wds[16];
  __shared__ float wvs[4][256];

  const int tid = threadIdx.x, wave = tid >> 6, lane = tid & 63;
  const int cl = lane & 15, g16 = lane >> 4;

  if (blockIdx.x >= 512) {
    // ---------- k56-user path (tid<256 active; all threads barrier) ----------
    const int b = blockIdx.x - 512;          // 0..63, 32 user rows each
    const __bf16* huf  = (const __bf16*)(ws + OFF_HUF);
    const __bf16* uw1f = (const __bf16*)(ws + OFF_UW1F);
    const __bf16* uw2f = (const __bf16*)(ws + OFF_UW2F);
    __bf16* l1f = (__bf16*)&bufA[0][0];      // 16 KB alias
    float*  l2p = (float*)&bufB[0][0];       // [4][32][2] alias
    const int cg4 = (tid >> 6) & 3;

    f32x4 acc[2][4] = {};
    if (tid < 256) {
      frag_gemm_acc_g<2, 8>(huf + (b >> 1) * 16384, (b & 1) * 2, uw1f + 8 * 16 * 512, acc);
#pragma unroll
      for (int g = 0; g < 2; ++g)
#pragma unroll
        for (int f = 0; f < 4; ++f) {
          const int col = cg4 * 64 + f * 16 + cl;
          const float b1 = upd_b1[col];
#pragma unroll
          for (int r = 0; r < 4; ++r) {
            float v = fmaxf(acc[g][f][r] + b1, 0.f);
            l1f[((col >> 5) * 2 + g) * 512 + (((col >> 3) & 3) * 16 + g16 * 4 + r) * 8 + (col & 7)] =
                (__bf16)v;
          }
        }
    }
    __syncthreads();

    if (tid < 256) {
      f32x4 a2[2][4] = {};
      for (int ks = 0; ks < 8; ++ks) {
        bf16x8 Af[2], Bf[4];
#pragma unroll
        for (int g = 0; g < 2; ++g)
          Af[g] = *(const bf16x8*)(l1f + ((ks * 2 + g) * 64 + lane) * 8);
#pragma unroll
        for (int f = 0; f < 4; ++f)
          Bf[f] = *(const bf16x8*)(uw2f + ((ks * 16 + cg4 * 4 + f) * 64 + lane) * 8);
#pragma unroll
        for (int g = 0; g < 2; ++g)
#pragma unroll
          for (int f = 0; f < 4; ++f)
            a2[g][f] = __builtin_amdgcn_mfma_f32_16x16x32_bf16(Af[g], Bf[f], a2[g][f], 0, 0, 0);
      }
      float d0[2][4] = {}, d1[2][4] = {};
#pragma unroll
      for (int f = 0; f < 4; ++f) {
        const int col = cg4 * 64 + f * 16 + cl;
        const float b2 = upd_b2[col];
        const float w0 = lin2_w[col], w1 = lin2_w[256 + col];
#pragma unroll
        for (int g = 0; g < 2; ++g)
#pragma unroll
          for (int r = 0; r < 4; ++r) {
            float hv = fmaxf(a2[g][f][r] + b2, 0.f);
            d0[g][r] += hv * w0;
            d1[g][r] += hv * w1;
          }
      }
#pragma unroll
      for (int mask = 1; mask < 16; mask <<= 1)
#pragma unroll
        for (int g = 0; g < 2; ++g)
#pragma unroll
          for (int r = 0; r < 4; ++r) {
            d0[g][r] += __shfl_xor(d0[g][r], mask);
            d1[g][r] += __shfl_xor(d1[g][r], mask);
          }
      if (cl == 0) {
#pragma unroll
        for (int g = 0; g < 2; ++g)
#pragma unroll
          for (int r = 0; r < 4; ++r) {
            l2p[(cg4 * 32 + g * 16 + g16 * 4 + r) * 2 + 0] = d0[g][r];
            l2p[(cg4 * 32 + g * 16 + g16 * 4 + r) * 2 + 1] = d1[g][r];
          }
      }
    }
    __syncthreads();
    if (tid < 32) {
      float s0 = l2p[(0 * 32 + tid) * 2 + 0] + l2p[(1 * 32 + tid) * 2 + 0] +
                 l2p[(2 * 32 + tid) * 2 + 0] + l2p[(3 * 32 + tid) * 2 + 0] + lin2_b[0];
      float s1 = l2p[(0 * 32 + tid) * 2 + 1] + l2p[(1 * 32 + tid) * 2 + 1] +
                 l2p[(2 * 32 + tid) * 2 + 1] + l2p[(3 * 32 + tid) * 2 + 1] + lin2_b[1];
      const int row = b * 32 + tid;
      out[row * 2 + 0] = 1.f / (1.f + expf(-s0));
      out[row * 2 + 1] = 1.f / (1.f + expf(-s1));
    }
    return;
  }

  // ---------- edge path (exact R4) ----------
  const char*  PUBF = (const char*)(ws + OFF_PUBF);
  const float* PB   = (const float*)(ws + OFF_PB);
  const float* spr  = (const float*)(ws + OFF_SPR);
  const float* vv   = (const float*)(ws + OFF_ATT) + 256;
  const char*  W2F  = (const char*)(ws + OFF_W2F);
  float* crec = (float*)(ws + OFF_CREC);

  const int m = blockIdx.x >> 3, ch = blockIdx.x & 7;
  const int rg = wave >> 2, cg = wave & 3;
  const int rot = (m + ch) & 7;            // de-hotspot rotation
  const float sm = spr[m];
  const char* Asrc = PUBF + ch * 131072;
  const float* pbm = PB + m * 256;

  // prologue: stage tile rot (repack A in regs, gl16 B)
  {
    bf16x8 araw = *(const bf16x8*)(Asrc + rot * 16384 + tid * 16);
    gl16(W2F + rot * 16384 + tid * 16, &bufB[0][tid * 16]);
    const float* pbp = pbm + rot * 32 + (tid >> 4 & 3) * 8;
    f32x4 p0 = *(const f32x4*)pbp, p1 = *(const f32x4*)(pbp + 4);
    bf16x8 a;
#pragma unroll
    for (int r = 0; r < 4; ++r) {
      a[r]     = (__bf16)fmaxf((float)araw[r]     + p0[r], 0.f);
      a[4 + r] = (__bf16)fmaxf((float)araw[4 + r] + p1[r], 0.f);
    }
    *(bf16x8*)(&bufA[0][tid * 16]) = a;
  }
  __syncthreads();

  f32x4 acc[4][4] = {};
  for (int i = 0; i < 8; ++i) {
    const int cur = i & 1;
    bf16x8 arn{};
    f32x4 pn0{}, pn1{};
    if (i < 7) {
      const int ksn = (i + 1 + rot) & 7;
      arn = *(const bf16x8*)(Asrc + ksn * 16384 + tid * 16);
      gl16(W2F + ksn * 16384 + tid * 16, &bufB[cur ^ 1][tid * 16]);
      const float* pbp = pbm + ksn * 32 + (tid >> 4 & 3) * 8;
      pn0 = *(const f32x4*)pbp;
      pn1 = *(const f32x4*)(pbp + 4);
    }
    bf16x8 Af[4], Bf[4];
#pragma unroll
    for (int g = 0; g < 4; ++g)
      Af[g] = *(const bf16x8*)(&bufA[cur][((rg * 4 + g) * 64 + lane) * 16]);
#pragma unroll
    for (int f = 0; f < 4; ++f)
      Bf[f] = *(const bf16x8*)(&bufB[cur][((cg * 4 + f) * 64 + lane) * 16]);
    __builtin_amdgcn_s_setprio(1);
#pragma unroll
    for (int g = 0; g < 4; ++g)
#pragma unroll
      for (int f = 0; f < 4; ++f)
        acc[g][f] = __builtin_amdgcn_mfma_f32_16x16x32_bf16(Af[g], Bf[f], acc[g][f], 0, 0, 0);
    __builtin_amdgcn_s_setprio(0);
    if (i < 7) {
      bf16x8 a;
#pragma unroll
      for (int r = 0; r < 4; ++r) {
        a[r]     = (__bf16)fmaxf((float)arn[r]     + pn0[r], 0.f);
        a[4 + r] = (__bf16)fmaxf((float)arn[4 + r] + pn1[r], 0.f);
      }
      *(bf16x8*)(&bufA[cur ^ 1][tid * 16]) = a;
    }
    __syncthreads();
  }

  // msg = relu(acc + b2); logit partial over this wave's 64 cols
  float p[4][4] = {};
#pragma unroll
  for (int f = 0; f < 4; ++f) {
    const int j = cg * 64 + f * 16 + cl;
    const float b2j = msg_b2[j], vj = vv[j];
#pragma unroll
    for (int g = 0; g < 4; ++g)
#pragma unroll
      for (int r = 0; r < 4; ++r) {
        float mv = fmaxf(acc[g][f][r] + b2j, 0.f);
        acc[g][f][r] = mv;
        p[g][r] += mv * vj;
      }
  }
#pragma unroll
  for (int mask = 1; mask < 16; mask <<= 1)
#pragma unroll
    for (int g = 0; g < 4; ++g)
#pragma unroll
      for (int r = 0; r < 4; ++r) p[g][r] += __shfl_xor(p[g][r], mask);
  if (cl == 0) {
#pragma unroll
    for (int g = 0; g < 4; ++g)
#pragma unroll
      for (int r = 0; r < 4; ++r) plds[wave][g * 16 + g16 * 4 + r] = p[g][r];
  }
  __syncthreads();

  float lr[4][4], wm = -3.4e38f;
#pragma unroll
  for (int g = 0; g < 4; ++g)
#pragma unroll
    for (int r = 0; r < 4; ++r) {
      int row = g * 16 + g16 * 4 + r;
      float l = plds[rg * 4 + 0][row] + plds[rg * 4 + 1][row] +
                plds[rg * 4 + 2][row] + plds[rg * 4 + 3][row] + sm;
      l = l > 0.f ? l : 0.2f * l;
      lr[g][r] = l;
      wm = fmaxf(wm, l);
    }
  wm = fmaxf(wm, __shfl_xor(wm, 16));
  wm = fmaxf(wm, __shfl_xor(wm, 32));
  if (lane == 0) redmax[wave] = wm;
  __syncthreads();
  float Mc = redmax[0];
#pragma unroll
  for (int i = 1; i < 16; ++i) Mc = fmaxf(Mc, redmax[i]);

  float e[4][4], ds = 0.f;
#pragma unroll
  for (int g = 0; g < 4; ++g)
#pragma unroll
    for (int r = 0; r < 4; ++r) { e[g][r] = __expf(lr[g][r] - Mc); ds += e[g][r]; }
  ds += __shfl_xor(ds, 16);
  ds += __shfl_xor(ds, 32);
  if (lane == 0) wds[wave] = ds;

#pragma unroll
  for (int f = 0; f < 4; ++f) {
    float w = 0.f;
#pragma unroll
    for (int g = 0; g < 4; ++g)
#pragma unroll
      for (int r = 0; r < 4; ++r) w += e[g][r] * acc[g][f][r];
    w += __shfl_xor(w, 16);
    w += __shfl_xor(w, 32);
    if (g16 == 0) wvs[rg][cg * 64 + f * 16 + cl] = w;
  }
  __syncthreads();

  float* rec = crec + (m * 8 + ch) * 260;
  if (tid < 256) rec[tid] = wvs[0][tid] + wvs[1][tid] + wvs[2][tid] + wvs[3][tid];
  if (tid == 0) rec[256] = Mc;
  if (tid == 1) rec[257] = wds[0] + wds[4] + wds[8] + wds[12];
}

// =====================================================================
// K56: UAV-only update MLP (2 blocks of 32 rows: agg combine + full)
// =====================================================================
__global__ __launch_bounds__(256) void k56_update(
    const float* __restrict__ upd_b1, const float* __restrict__ upd_b2,
    char* __restrict__ ws)
{
  const __bf16* huf  = (const __bf16*)(ws + OFF_HUF);
  const __bf16* uw1f = (const __bf16*)(ws + OFF_UW1F);
  const __bf16* uw2f = (const __bf16*)(ws + OFF_UW2F);

  __shared__ __align__(16) __bf16 l1f[8 * 2 * 512];
  __shared__ __align__(16) __bf16 aggf[8 * 2 * 512];
  __shared__ float scs[32][8];
  __shared__ float sS[32];

  const int b = blockIdx.x, tid = threadIdx.x;
  const int lane = tid & 63, cg = tid >> 6;
  const int cl = lane & 15, g16 = lane >> 4;

  const int m0 = b * 32;
  const float* crec = (const float*)(ws + OFF_CREC);
  if (tid < 32) {
    const int m = m0 + tid;
    float mx = -3.4e38f;
    for (int c = 0; c < 8; ++c) mx = fmaxf(mx, crec[(m * 8 + c) * 260 + 256]);
    float S = 0.f;
    for (int c = 0; c < 8; ++c) {
      float sc = __expf(crec[(m * 8 + c) * 260 + 256] - mx);
      scs[tid][c] = sc;
      S += sc * crec[(m * 8 + c) * 260 + 257];
    }
    sS[tid] = S;
  }
  __syncthreads();
  for (int ml = 0; ml < 32; ++ml) {
    float A = 0.f;
#pragma unroll
    for (int c = 0; c < 8; ++c) A += scs[ml][c] * crec[((m0 + ml) * 8 + c) * 260 + tid];
    float agg = A / sS[ml] * (1.f / 2048.f);
    aggf[((tid >> 5) * 2 + (ml >> 4)) * 512 + (((tid >> 3) & 3) * 16 + (ml & 15)) * 8 + (tid & 7)] =
        (__bf16)agg;
  }
  __syncthreads();

  f32x4 acc[2][4] = {};
  const int g0 = b * 2;
  const __bf16* hufu = huf + 32 * 16384;
  for (int ks = 0; ks < 8; ++ks) {
    bf16x8 Af[2], Bf[4];
#pragma unroll
    for (int g = 0; g < 2; ++g)
      Af[g] = *(const bf16x8*)(aggf + ((ks * 2 + g) * 64 + lane) * 8);
#pragma unroll
    for (int f = 0; f < 4; ++f)
      Bf[f] = *(const bf16x8*)(uw1f + ((ks * 16 + cg * 4 + f) * 64 + lane) * 8);
#pragma unroll
    for (int g = 0; g < 2; ++g)
#pragma unroll
      for (int f = 0; f < 4; ++f)
        acc[g][f] = __builtin_amdgcn_mfma_f32_16x16x32_bf16(Af[g], Bf[f], acc[g][f], 0, 0, 0);
  }
  for (int ks = 8; ks < 16; ++ks) {
    bf16x8 Af[2], Bf[4];
#pragma unroll
    for (int g = 0; g < 2; ++g)
      Af[g] = *(const bf16x8*)(hufu + (((ks - 8) * 4 + g0 + g) * 64 + lane) * 8);
#pragma unroll
    for (int f = 0; f < 4; ++f)
      Bf[f] = *(const bf16x8*)(uw1f + ((ks * 16 + cg * 4 + f) * 64 + lane) * 8);
#pragma unroll
    for (int g = 0; g < 2; ++g)
#pragma unroll
      for (int f = 0; f < 4; ++f)
        acc[g][f] = __builtin_amdgcn_mfma_f32_16x16x32_bf16(Af[g], Bf[f], acc[g][f], 0, 0, 0);
  }

#pragma unroll
  for (int g = 0; g < 2; ++g)
#pragma unroll
    for (int f = 0; f < 4; ++f) {
      const int col = cg * 64 + f * 16 + cl;
      const float b1 = upd_b1[col];
#pragma unroll
      for (int r = 0; r < 4; ++r) {
        float v = fmaxf(acc[g][f][r] + b1, 0.f);
        l1f[((col >> 5) * 2 + g) * 512 + (((col >> 3) & 3) * 16 + g16 * 4 + r) * 8 + (col & 7)] =
            (__bf16)v;
      }
    }
  __syncthreads();

  f32x4 a2[2][4] = {};
  for (int ks = 0; ks < 8; ++ks) {
    bf16x8 Af[2], Bf[4];
#pragma unroll
    for (int g = 0; g < 2; ++g)
      Af[g] = *(const bf16x8*)(l1f + ((ks * 2 + g) * 64 + lane) * 8);
#pragma unroll
    for (int f = 0; f < 4; ++f)
      Bf[f] = *(const bf16x8*)(uw2f + ((ks * 16 + cg * 4 + f) * 64 + lane) * 8);
#pragma unroll
    for (int g = 0; g < 2; ++g)
#pragma unroll
      for (int f = 0; f < 4; ++f)
        a2[g][f] = __builtin_amdgcn_mfma_f32_16x16x32_bf16(Af[g], Bf[f], a2[g][f], 0, 0, 0);
  }

  float* h2u = (float*)(ws + OFF_H2U);
#pragma unroll
  for (int g = 0; g < 2; ++g)
#pragma unroll
    for (int f = 0; f < 4; ++f) {
      const int col = cg * 64 + f * 16 + cl;
      const float b2 = upd_b2[col];
#pragma unroll
      for (int r = 0; r < 4; ++r) {
        const int rl = g * 16 + g16 * 4 + r;
        h2u[(m0 + rl) * 256 + col] = fmaxf(a2[g][f][r] + b2, 0.f);
      }
    }
}

// =====================================================================
// K7a: UAV LSTM gate partials, k-quartered. grid 256 = 64 m x 4 kq.
// =====================================================================
__global__ __launch_bounds__(256) void k7a_gates(char* __restrict__ ws)
{
  const float* h2u  = (const float*)(ws + OFF_H2U);
  const float* wihT = (const float*)(ws + OFF_WIHT);
  float* part = (float*)(ws + OFF_PART);
  const int m = blockIdx.x >> 2, kq = blockIdx.x & 3;
  const int tid = threadIdx.x;
  const int dir = tid >> 7, hc = tid & 127;
  __shared__ float xs[64];
  if (tid < 64) xs[tid] = h2u[m * 256 + kq * 64 + tid];
  __syncthreads();
  f32x4 a4 = {0.f, 0.f, 0.f, 0.f};
  for (int k = 0; k < 64; ++k) {
    float xv = xs[k];
    f32x4 wv4 = *(const f32x4*)(wihT + dir * 131072 + (kq * 64 + k) * 512 + hc * 4);
#pragma unroll
    for (int g = 0; g < 4; ++g) a4[g] += xv * wv4[g];
  }
  *(f32x4*)(part + (m * 4 + kq) * 1024 + dir * 512 + hc * 4) = a4;
}

// =====================================================================
// K7b: combine partials + LSTM nonlinearity + lin2 + sigmoid (64 blocks)
// =====================================================================
__global__ __launch_bounds__(256) void k7b_final(
    const float* __restrict__ uavl_b, const float* __restrict__ lin2_w,
    const float* __restrict__ lin2_b, float* __restrict__ out, char* __restrict__ ws)
{
  const float* part = (const float*)(ws + OFF_PART);
  const int m = blockIdx.x, tid = threadIdx.x;
  const int dir = tid >> 7, hc = tid & 127;
  f32x4 a4 = {0.f, 0.f, 0.f, 0.f};
#pragma unroll
  for (int kq = 0; kq < 4; ++kq) {
    f32x4 p = *(const f32x4*)(part + (m * 4 + kq) * 1024 + dir * 512 + hc * 4);
#pragma unroll
    for (int g = 0; g < 4; ++g) a4[g] += p[g];
  }
  float bb[4];
#pragma unroll
  for (int g = 0; g < 4; ++g) bb[g] = uavl_b[dir * 512 + g * 128 + hc];
  __shared__ float uo[256];
  float ii = sigm(a4[0] + bb[0]);
  float gg = tanhf(a4[2] + bb[2]);
  float oo = sigm(a4[3] + bb[3]);
  float cc = ii * gg;
  uo[dir * 128 + hc] = oo * tanhf(cc);
  __syncthreads();
  float p0 = uo[tid] * lin2_w[tid];
  float p1 = uo[tid] * lin2_w[256 + tid];
#pragma unroll
  for (int mask = 1; mask < 64; mask <<= 1) {
    p0 += __shfl_xor(p0, mask);
    p1 += __shfl_xor(p1, mask);
  }
  __shared__ float r0s[4], r1s[4];
  const int lane = tid & 63, wv = tid >> 6;
  if (lane == 0) { r0s[wv] = p0; r1s[wv] = p1; }
  __syncthreads();
  if (tid == 0) {
    float d0 = r0s[0] + r0s[1] + r0s[2] + r0s[3] + lin2_b[0];
    float d1 = r1s[0] + r1s[1] + r1s[2] + r1s[3] + lin2_b[1];
    out[(NUQ + m) * 2 + 0] = 1.f / (1.f + expf(-d0));
    out[(NUQ + m) * 2 + 1] = 1.f / (1.f + expf(-d1));
  }
}

// =====================================================================
extern "C" void kernel_launch(void* const* d_in, const int* in_sizes, int n_in,
                              void* d_out, int out_size, void* d_ws, size_t ws_size,
                              hipStream_t stream)
{
  const float* x         = (const float*)d_in[0];
  const float* ul_wih    = (const float*)d_in[3];
  const float* ul_whh    = (const float*)d_in[4];
  const float* ul_b      = (const float*)d_in[5];
  const float* uav_lin_w = (const float*)d_in[6];
  const float* uav_lin_b = (const float*)d_in[7];
  const float* msg_w1    = (const float*)d_in[8];
  const float* msg_b1    = (const float*)d_in[9];
  const float* msg_w2    = (const float*)d_in[10];
  const float* msg_b2    = (const float*)d_in[11];
  const float* wq_w      = (const float*)d_in[12];
  const float* wq_b      = (const float*)d_in[13];
  const float* wr_w      = (const float*)d_in[14];
  const float* wr_b      = (const float*)d_in[15];
  const float* att_w     = (const float*)d_in[16];
  const float* att_b     = (const float*)d_in[17];
  const float* upd_w1    = (const float*)d_in[18];
  const float* upd_b1    = (const float*)d_in[19];
  const float* upd_w2    = (const float*)d_in[20];
  const float* upd_b2    = (const float*)d_in[21];
  const float* uavl_wih  = (const float*)d_in[22];
  const float* uavl_b    = (const float*)d_in[24];
  const float* lin2_w    = (const float*)d_in[25];
  const float* lin2_b    = (const float*)d_in[26];
  char* ws = (char*)d_ws;
  float* out = (float*)d_out;

  k0_prep<<<dim3(161), dim3(256), 0, stream>>>(ul_whh, uavl_wih, msg_w1, msg_w2, upd_w1,
                                               upd_w2, att_w, att_b, wq_w, wq_b, wr_w, wr_b, ws);
  k1_embed<<<dim3(260), dim3(256), 0, stream>>>(x, ul_wih, ul_b, uav_lin_w, uav_lin_b, ws);
  k2_proj<<<dim3(66), dim3(256), 0, stream>>>(msg_b1, ws);
  k3_edge<<<dim3(576), dim3(1024), 0, stream>>>(msg_b2, upd_b1, upd_b2, lin2_w, lin2_b, out, ws);
  k56_update<<<dim3(2), dim3(256), 0, stream>>>(upd_b1, upd_b2, ws);
  k7a_gates<<<dim3(256), dim3(256), 0, stream>>>(ws);
  k7b_final<<<dim3(64), dim3(256), 0, stream>>>(uavl_b, lin2_w, lin2_b, out, ws);
}

// Round 12
// 92.477 us; speedup vs baseline: 1.0925x; 1.0925x over previous
//
#include <hip/hip_runtime.h>
#include <hip/hip_bf16.h>
#include <math.h>

#define UQ   1024
#define NUQ  2048
#define MQ   64
#define NN   2112
#define HD   256

typedef __attribute__((ext_vector_type(4))) float f32x4;
typedef __attribute__((ext_vector_type(2))) float f32x2;
typedef __attribute__((ext_vector_type(8))) __bf16 bf16x8;

// ---- workspace layout (bytes) ----
#define OFF_HB    0u          // UAV h f32 [64][256]                65,536
#define OFF_HUF   65536u      // h frag bf16 [33][8][4][512]     1,081,344
#define OFF_PUBF  1146880u    // P_user frag fp8 [8][8][16][512B]  524,288
#define OFF_PB    2195456u    // P_uav+b1 f32 [64][256]             65,536
#define OFF_SPR   2260992u    // s'_m f32 [64]                         256
#define OFF_ATT   2261248u    // wqa[256], v[256], const0            2,304
#define OFF_WHHT  2263552u    // user WhhT2 f32 [2][128][512]      524,288
#define OFF_WIHT  2787840u    // uav WihT2 f32 [2][256][512]     1,048,576
#define OFF_W1F   3836416u    // msg_w1 frag bf16 [16][16][512]    262,144
#define OFF_W2F   4098560u    // msg_w2 frag fp8 [8][16][512B]      65,536
#define OFF_UW1F  4229632u    // upd_w1 frag bf16 [16][16][512]    262,144
#define OFF_UW2F  4491776u    // upd_w2 frag bf16 [8][16][512]     131,072
#define OFF_CREC  4622848u    // chunk rec f32 [512][260]          532,480
#define OFF_H2U   5155328u    // h2 UAV f32 [64][256]               65,536
#define OFF_PART  5220864u    // uav-lstm gate partials f32      1,048,576
// total ~6.3 MB

__device__ __forceinline__ float sigm(float v) { return 1.f / (1.f + expf(-v)); }

// fragment-major index helpers: element (row, k)
__device__ __forceinline__ int huf_idx(int row, int k) {   // [33][8][4][512]
  return (((row >> 6) * 8 + (k >> 5)) * 4 + ((row >> 4) & 3)) * 512 +
         (((k >> 3) & 3) * 16 + (row & 15)) * 8 + (k & 7);
}

__device__ __forceinline__ void gl16(const void* g, void* l) {
  __builtin_amdgcn_global_load_lds((const __attribute__((address_space(1))) void*)g,
                                   (__attribute__((address_space(3))) void*)l, 16, 0, 0);
}

__device__ __forceinline__ int2 pack_fp8x8(const float v[8]) {
  int lo = 0, hi = 0;
  lo = __builtin_amdgcn_cvt_pk_fp8_f32(v[0], v[1], lo, false);
  lo = __builtin_amdgcn_cvt_pk_fp8_f32(v[2], v[3], lo, true);
  hi = __builtin_amdgcn_cvt_pk_fp8_f32(v[4], v[5], hi, false);
  hi = __builtin_amdgcn_cvt_pk_fp8_f32(v[6], v[7], hi, true);
  return make_int2(lo, hi);
}

// =====================================================================
// K0: weight preprocessing — LDS-tiled transposes + fragment-major casts
// =====================================================================
__device__ void tile_transpose_perm(const float* __restrict__ in, int in_ld,
                                    float* __restrict__ out, int out_ld,
                                    int k0, int c0) {
  __shared__ float ldt[64][68];
  const int t = threadIdx.x;
  {
    const int ci = t >> 2, kq = t & 3;
    const int c = c0 + ci;
    const int row = (c & 3) * 128 + (c >> 2);
    const float* src = in + row * in_ld + k0 + kq * 16;
#pragma unroll
    for (int e = 0; e < 4; ++e)
      *(f32x4*)&ldt[ci][kq * 16 + e * 4] = *(const f32x4*)(src + e * 4);
  }
  __syncthreads();
  {
    const int kk = t >> 2, cq = t & 3;
    float* dst = out + (k0 + kk) * out_ld + c0 + cq * 16;
#pragma unroll
    for (int e4 = 0; e4 < 4; ++e4) {
      f32x4 v;
#pragma unroll
      for (int j = 0; j < 4; ++j) v[j] = ldt[cq * 16 + e4 * 4 + j][kk];
      *(f32x4*)(dst + e4 * 4) = v;
    }
  }
}

template<int K>
__device__ void frag_cast16(const float* __restrict__ W, int j0, __bf16* __restrict__ frag) {
  __shared__ float ldc[16][K + 4];
  const int t = threadIdx.x;
  {
    const int jr = t >> 4, kq = t & 15;
    const float* src = W + (j0 + jr) * K + kq * (K / 16);
#pragma unroll
    for (int e = 0; e < K / 64; ++e)
      *(f32x4*)&ldc[jr][kq * (K / 16) + e * 4] = *(const f32x4*)(src + e * 4);
  }
  __syncthreads();
  const int f = j0 >> 4;
  constexpr int nks = K >> 5;
  constexpr int thr_per_ks = 256 / nks;
  constexpr int q_per_thr = 512 / thr_per_ks;
  const int ks = t / thr_per_ks;
  const int q0 = (t % thr_per_ks) * q_per_thr;
#pragma unroll
  for (int h = 0; h < q_per_thr / 8; ++h) {
    bf16x8 v;
#pragma unroll
    for (int e = 0; e < 8; ++e) {
      int q = q0 + h * 8 + e;
      int lane = q >> 3;
      v[e] = (__bf16)ldc[lane & 15][ks * 32 + (lane >> 4) * 8 + (q & 7)];
    }
    *(bf16x8*)(frag + (ks * 16 + f) * 512 + q0 + h * 8) = v;
  }
}

// fp8 variant for msg_w2 (K=256)
__device__ void frag_cast16_fp8(const float* __restrict__ W, int j0, char* __restrict__ frag) {
  __shared__ float ldc[16][260];
  const int t = threadIdx.x;
  {
    const int jr = t >> 4, kq = t & 15;
    const float* src = W + (j0 + jr) * 256 + kq * 16;
#pragma unroll
    for (int e = 0; e < 4; ++e)
      *(f32x4*)&ldc[jr][kq * 16 + e * 4] = *(const f32x4*)(src + e * 4);
  }
  __syncthreads();
  const int f = j0 >> 4;
  const int ks = t >> 5;            // 8 ks, 32 thr each
  const int q0 = (t & 31) * 16;     // 16 elems per thread
#pragma unroll
  for (int h = 0; h < 2; ++h) {
    const int qb = q0 + h * 8;
    const int lane = qb >> 3;
    float v[8];
#pragma unroll
    for (int e = 0; e < 8; ++e)
      v[e] = ldc[lane & 15][ks * 32 + (lane >> 4) * 8 + e];
    *(int2*)(frag + (ks * 16 + f) * 512 + qb) = pack_fp8x8(v);
  }
}

__global__ __launch_bounds__(256) void k0_prep(
    const float* __restrict__ ul_whh, const float* __restrict__ uavl_wih,
    const float* __restrict__ msg_w1, const float* __restrict__ msg_w2,
    const float* __restrict__ upd_w1, const float* __restrict__ upd_w2,
    const float* __restrict__ att_w,  const float* __restrict__ att_b,
    const float* __restrict__ wq_w,   const float* __restrict__ wq_b,
    const float* __restrict__ wr_w,   const float* __restrict__ wr_b,
    char* __restrict__ ws)
{
  const int b = blockIdx.x, t = threadIdx.x;
  if (b < 32) {
    const int dir = b >> 4, tile = b & 15;
    tile_transpose_perm(ul_whh + dir * 65536, 128,
                        (float*)(ws + OFF_WHHT) + dir * 65536, 512,
                        (tile >> 3) * 64, (tile & 7) * 64);
  } else if (b < 96) {
    const int b2 = b - 32, dir = b2 >> 5, tile = b2 & 31;
    tile_transpose_perm(uavl_wih + dir * 131072, 256,
                        (float*)(ws + OFF_WIHT) + dir * 131072, 512,
                        (tile >> 3) * 64, (tile & 7) * 64);
  } else if (b < 112) {
    frag_cast16_fp8(msg_w2, (b - 96) * 16, (char*)(ws + OFF_W2F));
  } else if (b < 128) {
    frag_cast16<512>(msg_w1, (b - 112) * 16, (__bf16*)(ws + OFF_W1F));
  } else if (b < 144) {
    frag_cast16<512>(upd_w1, (b - 128) * 16, (__bf16*)(ws + OFF_UW1F));
  } else if (b < 160) {
    frag_cast16<256>(upd_w2, (b - 144) * 16, (__bf16*)(ws + OFF_UW2F));
  } else {
    float* wqa = (float*)(ws + OFF_ATT);
    float* vv  = wqa + 256;
    float* c0  = wqa + 512;
    float sa = 0.f, sr = 0.f;
    for (int j = 0; j < 256; ++j) {
      sa += att_w[j]       * wq_w[j * 256 + t];
      sr += att_w[256 + j] * wr_w[j * 256 + t];
    }
    wqa[t] = sa; vv[t] = sr;
    __shared__ float red[256];
    red[t] = att_w[t] * wq_b[t] + att_w[256 + t] * wr_b[t];
    __syncthreads();
    for (int s = 128; s > 0; s >>= 1) { if (t < s) red[t] += red[t + s]; __syncthreads(); }
    if (t == 0) c0[0] = red[0] + att_b[0];
  }
}

// =====================================================================
// K1: user BiLSTM (4 users/block, coalesced frag stores) + UAV embed
// =====================================================================
__global__ __launch_bounds__(256) void k1_embed(
    const float* __restrict__ x, const float* __restrict__ ul_wih,
    const float* __restrict__ ul_b, const float* __restrict__ uav_lin_w,
    const float* __restrict__ uav_lin_b, char* __restrict__ ws)
{
  __bf16* huf = (__bf16*)(ws + OFF_HUF);
  const int b = blockIdx.x, tid = threadIdx.x;
  if (b < 256) {
    const float* whhT = (const float*)(ws + OFF_WHHT);
    const int dir = tid >> 7, hc = tid & 127;
    const int u0 = b * 4;
    float wx[4], wy[4], bb[4];
#pragma unroll
    for (int g = 0; g < 4; ++g) {
      int row = g * 128 + hc;
      wx[g] = ul_wih[dir * 1024 + row * 2 + 0];
      wy[g] = ul_wih[dir * 1024 + row * 2 + 1];
      bb[g] = ul_b[dir * 512 + row];
    }
    __shared__ float h1s[2][128][4];
    __shared__ float hout[8][260];
    float c1[4], h1v[4], in1x[4], in1y[4];
#pragma unroll
    for (int uu = 0; uu < 4; ++uu) {
      int u = u0 + uu;
      float ax = x[u * 2], ay = x[u * 2 + 1];
      float bx = x[(UQ + u) * 2], by = x[(UQ + u) * 2 + 1];
      float i0x = dir ? bx : ax, i0y = dir ? by : ay;
      in1x[uu] = dir ? ax : bx; in1y[uu] = dir ? ay : by;
      float gv[4];
#pragma unroll
      for (int g = 0; g < 4; ++g) gv[g] = wx[g] * i0x + wy[g] * i0y + bb[g];
      float ii = sigm(gv[0]), gg = tanhf(gv[2]), oo = sigm(gv[3]);
      c1[uu] = ii * gg;
      h1v[uu] = oo * tanhf(c1[uu]);
      h1s[dir][hc][uu] = h1v[uu];
    }
    __syncthreads();
    float acc[4][4];
#pragma unroll
    for (int uu = 0; uu < 4; ++uu)
#pragma unroll
      for (int g = 0; g < 4; ++g) acc[uu][g] = wx[g] * in1x[uu] + wy[g] * in1y[uu] + bb[g];
#pragma unroll 4
    for (int k = 0; k < 128; ++k) {
      f32x4 hv  = *(const f32x4*)&h1s[dir][k][0];
      f32x4 wv4 = *(const f32x4*)(whhT + dir * 65536 + k * 512 + hc * 4);
#pragma unroll
      for (int uu = 0; uu < 4; ++uu)
#pragma unroll
        for (int g = 0; g < 4; ++g) acc[uu][g] += hv[uu] * wv4[g];
    }
    const int col = dir * 128 + hc;
#pragma unroll
    for (int uu = 0; uu < 4; ++uu) {
      float ii = sigm(acc[uu][0]), ff = sigm(acc[uu][1]);
      float gg = tanhf(acc[uu][2]), oo = sigm(acc[uu][3]);
      float c2 = ff * c1[uu] + ii * gg;
      float h2v = oo * tanhf(c2);
      float va = dir ? h2v : h1v[uu];   // node u
      float vb = dir ? h1v[uu] : h2v;   // node UQ+u
      hout[uu][col] = va;
      hout[4 + uu][col] = vb;
    }
    __syncthreads();
    {
      const int lr = tid >> 5, c = tid & 31;
      bf16x8 v;
#pragma unroll
      for (int e = 0; e < 8; ++e) v[e] = (__bf16)hout[lr][c * 8 + e];
      const int node = (lr < 4) ? (u0 + lr) : (UQ + u0 + lr - 4);
      *(bf16x8*)(huf + huf_idx(node, c * 8)) = v;
    }
  } else {
    float* hb = (float*)(ws + OFF_HB);
    const int j = tid;
    const int mb = (b - 256) * 16;
    for (int m = mb; m < mb + 16; ++m) {
      float xa = x[(NUQ + m) * 2], xb = x[(NUQ + m) * 2 + 1];
      float val = xa * uav_lin_w[j * 2] + xb * uav_lin_w[j * 2 + 1] + uav_lin_b[j];
      hb[m * 256 + j] = val;
      huf[huf_idx(NUQ + m, j)] = (__bf16)val;
    }
  }
}

// =====================================================================
// frag-major MFMA GEMM core: 4 waves (cg over 64-col groups), G*16 rows
// =====================================================================
template<int G, int NKS>
__device__ __forceinline__ void frag_gemm_acc_g(const __bf16* __restrict__ Abase, int g0,
                                                const __bf16* __restrict__ Bbase,
                                                f32x4 acc[G][4]) {
  const int lane = threadIdx.x & 63;
  const int cg = (threadIdx.x >> 6) & 3;
  for (int ks = 0; ks < NKS; ++ks) {
    bf16x8 Af[G], Bf[4];
#pragma unroll
    for (int g = 0; g < G; ++g)
      Af[g] = *(const bf16x8*)(Abase + ((ks * 4 + g0 + g) * 64 + lane) * 8);
#pragma unroll
    for (int f = 0; f < 4; ++f)
      Bf[f] = *(const bf16x8*)(Bbase + ((ks * 16 + cg * 4 + f) * 64 + lane) * 8);
#pragma unroll
    for (int g = 0; g < G; ++g)
#pragma unroll
      for (int f = 0; f < 4; ++f)
        acc[g][f] = __builtin_amdgcn_mfma_f32_16x16x32_bf16(Af[g], Bf[f], acc[g][f], 0, 0, 0);
  }
}

// =====================================================================
// K2: P_user frag fp8 (64 x 32-row blocks, LDS-coalesced stores),
//     P_uav+b1 f32 (1), s'_m (1)
// =====================================================================
__global__ __launch_bounds__(256) void k2_proj(const float* __restrict__ msg_b1,
                                               char* __restrict__ ws)
{
  const __bf16* huf = (const __bf16*)(ws + OFF_HUF);
  const __bf16* w1f = (const __bf16*)(ws + OFF_W1F);
  const int b = blockIdx.x;
  const int tid = threadIdx.x;
  const int lane = tid & 63, cg = tid >> 6;
  const int cl = lane & 15, g16 = lane >> 4;
  if (b < 64) {
    f32x4 acc[2][4] = {};
    frag_gemm_acc_g<2, 8>(huf + (b >> 1) * 16384, (b & 1) * 2, w1f + 65536, acc);
    __shared__ float ldt[32][264];
#pragma unroll
    for (int g = 0; g < 2; ++g)
#pragma unroll
      for (int f = 0; f < 4; ++f)
#pragma unroll
        for (int r = 0; r < 4; ++r)
          ldt[g * 16 + g16 * 4 + r][cg * 64 + f * 16 + cl] = acc[g][f][r];
    __syncthreads();
    char* pubf = (char*)(ws + OFF_PUBF);
    const int c2 = b >> 3, r16base = (b & 7) * 2;
#pragma unroll
    for (int p = 0; p < 4; ++p) {
      const int region = p * 4 + (tid >> 6);       // 0..15
      const int ks = region >> 1, r16l = region & 1;
      const int row15 = tid & 15, kg = (tid >> 4) & 3;
      const int row = r16l * 16 + row15;
      float v[8];
#pragma unroll
      for (int j = 0; j < 8; ++j) v[j] = ldt[row][ks * 32 + kg * 8 + j];
      const int dst = ((c2 * 8 + ks) * 16 + (r16base + r16l)) * 512 + (kg * 16 + row15) * 8;
      *(int2*)(pubf + dst) = pack_fp8x8(v);
    }
  } else if (b == 64) {
    f32x4 acc[4][4] = {};
    frag_gemm_acc_g<4, 8>(huf + 32 * 16384, 0, w1f, acc);
    float* pb = (float*)(ws + OFF_PB);
#pragma unroll
    for (int g = 0; g < 4; ++g)
#pragma unroll
      for (int f = 0; f < 4; ++f)
#pragma unroll
        for (int r = 0; r < 4; ++r) {
          int row = g * 16 + g16 * 4 + r;
          int col = cg * 64 + f * 16 + cl;
          pb[row * 256 + col] = acc[g][f][r] + msg_b1[col];
        }
  } else {
    const float* hb  = (const float*)(ws + OFF_HB);
    const float* wqa = (const float*)(ws + OFF_ATT);
    const float* c0  = wqa + 512;
    float* spr = (float*)(ws + OFF_SPR);
    if (tid < 64) {
      float s = 0.f;
      for (int k = 0; k < 256; ++k) s += hb[tid * 256 + k] * wqa[k];
      spr[tid] = s + c0[0];
    }
  }
}

// =====================================================================
// K3: edge msg layer-2 in FP8 (mfma_f32_16x16x32_fp8_fp8) + attention
// + chunk softmax. Proven R4/R5 shape: 1024 thr = 16 waves (4rg x 4cg),
// grid 512 = 64m x 8ch, gl16-dbuf B(fp8), staging-time repack of A
// (fp8 unpack -> +PB -> relu -> fp8 pack), ks-rotation, setprio.
// Half the L2 traffic of the bf16 version (A 32MB + B 32MB).
// =====================================================================
__global__ __launch_bounds__(1024, 2) void k3_edge(const float* __restrict__ msg_b2,
                                                   char* __restrict__ ws)
{
  const char*  PUBF = (const char*)(ws + OFF_PUBF);
  const float* PB   = (const float*)(ws + OFF_PB);
  const float* spr  = (const float*)(ws + OFF_SPR);
  const float* vv   = (const float*)(ws + OFF_ATT) + 256;
  const char*  W2F  = (const char*)(ws + OFF_W2F);
  float* crec = (float*)(ws + OFF_CREC);

  __shared__ __align__(16) char bufA[2][8192];
  __shared__ __align__(16) char bufB[2][8192];
  __shared__ float plds[16][64];
  __shared__ float redmax[16], wds[16];
  __shared__ float wvs[4][256];

  const int m = blockIdx.x >> 3, ch = blockIdx.x & 7;
  const int tid = threadIdx.x, wave = tid >> 6, lane = tid & 63;
  const int cl = lane & 15, g16 = lane >> 4;
  const int rg = wave >> 2, cg = wave & 3;
  const int rot = (m + ch) & 7;
  const float sm = spr[m];
  const char* Asrc = PUBF + ch * 65536;
  const float* pbm = PB + m * 256;
  const int bq = ((tid >> 4) & 3) * 8;

  auto repack = [](int2 raw, f32x4 p0, f32x4 p1) -> int2 {
    f32x2 a01 = __builtin_amdgcn_cvt_pk_f32_fp8(raw.x, false);
    f32x2 a23 = __builtin_amdgcn_cvt_pk_f32_fp8(raw.x, true);
    f32x2 a45 = __builtin_amdgcn_cvt_pk_f32_fp8(raw.y, false);
    f32x2 a67 = __builtin_amdgcn_cvt_pk_f32_fp8(raw.y, true);
    float v[8];
    v[0] = fmaxf(a01.x + p0[0], 0.f);
    v[1] = fmaxf(a01.y + p0[1], 0.f);
    v[2] = fmaxf(a23.x + p0[2], 0.f);
    v[3] = fmaxf(a23.y + p0[3], 0.f);
    v[4] = fmaxf(a45.x + p1[0], 0.f);
    v[5] = fmaxf(a45.y + p1[1], 0.f);
    v[6] = fmaxf(a67.x + p1[2], 0.f);
    v[7] = fmaxf(a67.y + p1[3], 0.f);
    return pack_fp8x8(v);
  };

  // prologue: stage tile `rot` (repack A in regs, gl16 B for waves 0..7)
  {
    int2 raw = *(const int2*)(Asrc + rot * 8192 + tid * 8);
    if (wave < 8)
      gl16(W2F + rot * 8192 + wave * 1024 + lane * 16, &bufB[0][wave * 1024 + lane * 16]);
    const float* pbp = pbm + rot * 32 + bq;
    f32x4 p0 = *(const f32x4*)pbp, p1 = *(const f32x4*)(pbp + 4);
    *(int2*)(&bufA[0][tid * 8]) = repack(raw, p0, p1);
  }
  __syncthreads();

  f32x4 acc[4][4] = {};
  for (int i = 0; i < 8; ++i) {
    const int cur = i & 1;
    int2 arn = make_int2(0, 0);
    f32x4 pn0{}, pn1{};
    if (i < 7) {
      const int ksn = (i + 1 + rot) & 7;
      arn = *(const int2*)(Asrc + ksn * 8192 + tid * 8);
      if (wave < 8)
        gl16(W2F + ksn * 8192 + wave * 1024 + lane * 16, &bufB[cur ^ 1][wave * 1024 + lane * 16]);
      const float* pbp = pbm + ksn * 32 + bq;
      pn0 = *(const f32x4*)pbp;
      pn1 = *(const f32x4*)(pbp + 4);
    }
    long Af[4], Bf[4];
#pragma unroll
    for (int g = 0; g < 4; ++g)
      Af[g] = *(const long*)(&bufA[cur][((rg * 4 + g) * 64 + lane) * 8]);
#pragma unroll
    for (int f = 0; f < 4; ++f)
      Bf[f] = *(const long*)(&bufB[cur][((cg * 4 + f) * 64 + lane) * 8]);
    __builtin_amdgcn_s_setprio(1);
#pragma unroll
    for (int g = 0; g < 4; ++g)
#pragma unroll
      for (int f = 0; f < 4; ++f)
        acc[g][f] = __builtin_amdgcn_mfma_f32_16x16x32_fp8_fp8(Af[g], Bf[f], acc[g][f], 0, 0, 0);
    __builtin_amdgcn_s_setprio(0);
    if (i < 7) {
      *(int2*)(&bufA[cur ^ 1][tid * 8]) = repack(arn, pn0, pn1);
    }
    __syncthreads();
  }

  // msg = relu(acc + b2); logit partial over this wave's 64 cols
  float p[4][4] = {};
#pragma unroll
  for (int f = 0; f < 4; ++f) {
    const int j = cg * 64 + f * 16 + cl;
    const float b2j = msg_b2[j], vj = vv[j];
#pragma unroll
    for (int g = 0; g < 4; ++g)
#pragma unroll
      for (int r = 0; r < 4; ++r) {
        float mv = fmaxf(acc[g][f][r] + b2j, 0.f);
        acc[g][f][r] = mv;
        p[g][r] += mv * vj;
      }
  }
#pragma unroll
  for (int mask = 1; mask < 16; mask <<= 1)
#pragma unroll
    for (int g = 0; g < 4; ++g)
#pragma unroll
      for (int r = 0; r < 4; ++r) p[g][r] += __shfl_xor(p[g][r], mask);
  if (cl == 0) {
#pragma unroll
    for (int g = 0; g < 4; ++g)
#pragma unroll
      for (int r = 0; r < 4; ++r) plds[wave][g * 16 + g16 * 4 + r] = p[g][r];
  }
  __syncthreads();

  float lr[4][4], wm = -3.4e38f;
#pragma unroll
  for (int g = 0; g < 4; ++g)
#pragma unroll
    for (int r = 0; r < 4; ++r) {
      int row = g * 16 + g16 * 4 + r;
      float l = plds[rg * 4 + 0][row] + plds[rg * 4 + 1][row] +
                plds[rg * 4 + 2][row] + plds[rg * 4 + 3][row] + sm;
      l = l > 0.f ? l : 0.2f * l;
      lr[g][r] = l;
      wm = fmaxf(wm, l);
    }
  wm = fmaxf(wm, __shfl_xor(wm, 16));
  wm = fmaxf(wm, __shfl_xor(wm, 32));
  if (lane == 0) redmax[wave] = wm;
  __syncthreads();
  float Mc = redmax[0];
#pragma unroll
  for (int i = 1; i < 16; ++i) Mc = fmaxf(Mc, redmax[i]);

  float e[4][4], ds = 0.f;
#pragma unroll
  for (int g = 0; g < 4; ++g)
#pragma unroll
    for (int r = 0; r < 4; ++r) { e[g][r] = __expf(lr[g][r] - Mc); ds += e[g][r]; }
  ds += __shfl_xor(ds, 16);
  ds += __shfl_xor(ds, 32);
  if (lane == 0) wds[wave] = ds;

#pragma unroll
  for (int f = 0; f < 4; ++f) {
    float w = 0.f;
#pragma unroll
    for (int g = 0; g < 4; ++g)
#pragma unroll
      for (int r = 0; r < 4; ++r) w += e[g][r] * acc[g][f][r];
    w += __shfl_xor(w, 16);
    w += __shfl_xor(w, 32);
    if (g16 == 0) wvs[rg][cg * 64 + f * 16 + cl] = w;
  }
  __syncthreads();

  float* rec = crec + (m * 8 + ch) * 260;
  if (tid < 256) rec[tid] = wvs[0][tid] + wvs[1][tid] + wvs[2][tid] + wvs[3][tid];
  if (tid == 0) rec[256] = Mc;
  if (tid == 1) rec[257] = wds[0] + wds[4] + wds[8] + wds[12];
}

// =====================================================================
// K56: fused update MLP + user lin2+sigmoid. 66 blocks of 32 rows:
// b<64 users (h-half layer1); b=64,65: 32 UAVs each (agg combine + full).
// =====================================================================
__global__ __launch_bounds__(256) void k56_update(
    const float* __restrict__ upd_b1, const float* __restrict__ upd_b2,
    const float* __restrict__ lin2_w, const float* __restrict__ lin2_b,
    float* __restrict__ out, char* __restrict__ ws)
{
  const __bf16* huf  = (const __bf16*)(ws + OFF_HUF);
  const __bf16* uw1f = (const __bf16*)(ws + OFF_UW1F);
  const __bf16* uw2f = (const __bf16*)(ws + OFF_UW2F);

  __shared__ __align__(16) __bf16 l1f[8 * 2 * 512];
  __shared__ __align__(16) __bf16 aggf[8 * 2 * 512];
  __shared__ float scs[32][8];
  __shared__ float sS[32];
  __shared__ float l2p[4][32][2];

  const int b = blockIdx.x, tid = threadIdx.x;
  const int lane = tid & 63, cg = tid >> 6;
  const int cl = lane & 15, g16 = lane >> 4;

  f32x4 acc[2][4] = {};
  if (b < 64) {
    frag_gemm_acc_g<2, 8>(huf + (b >> 1) * 16384, (b & 1) * 2, uw1f + 8 * 16 * 512, acc);
  } else {
    const int m0 = (b - 64) * 32;
    const float* crec = (const float*)(ws + OFF_CREC);
    if (tid < 32) {
      const int m = m0 + tid;
      float mx = -3.4e38f;
      for (int c = 0; c < 8; ++c) mx = fmaxf(mx, crec[(m * 8 + c) * 260 + 256]);
      float S = 0.f;
      for (int c = 0; c < 8; ++c) {
        float sc = __expf(crec[(m * 8 + c) * 260 + 256] - mx);
        scs[tid][c] = sc;
        S += sc * crec[(m * 8 + c) * 260 + 257];
      }
      sS[tid] = S;
    }
    __syncthreads();
    for (int ml = 0; ml < 32; ++ml) {
      float A = 0.f;
#pragma unroll
      for (int c = 0; c < 8; ++c) A += scs[ml][c] * crec[((m0 + ml) * 8 + c) * 260 + tid];
      float agg = A / sS[ml] * (1.f / 2048.f);
      aggf[((tid >> 5) * 2 + (ml >> 4)) * 512 + (((tid >> 3) & 3) * 16 + (ml & 15)) * 8 + (tid & 7)] =
          (__bf16)agg;
    }
    __syncthreads();
    const int g0 = (b - 64) * 2;
    const __bf16* hufu = huf + 32 * 16384;
    for (int ks = 0; ks < 8; ++ks) {
      bf16x8 Af[2], Bf[4];
#pragma unroll
      for (int g = 0; g < 2; ++g)
        Af[g] = *(const bf16x8*)(aggf + ((ks * 2 + g) * 64 + lane) * 8);
#pragma unroll
      for (int f = 0; f < 4; ++f)
        Bf[f] = *(const bf16x8*)(uw1f + ((ks * 16 + cg * 4 + f) * 64 + lane) * 8);
#pragma unroll
      for (int g = 0; g < 2; ++g)
#pragma unroll
        for (int f = 0; f < 4; ++f)
          acc[g][f] = __builtin_amdgcn_mfma_f32_16x16x32_bf16(Af[g], Bf[f], acc[g][f], 0, 0, 0);
    }
    for (int ks = 8; ks < 16; ++ks) {
      bf16x8 Af[2], Bf[4];
#pragma unroll
      for (int g = 0; g < 2; ++g)
        Af[g] = *(const bf16x8*)(hufu + (((ks - 8) * 4 + g0 + g) * 64 + lane) * 8);
#pragma unroll
      for (int f = 0; f < 4; ++f)
        Bf[f] = *(const bf16x8*)(uw1f + ((ks * 16 + cg * 4 + f) * 64 + lane) * 8);
#pragma unroll
      for (int g = 0; g < 2; ++g)
#pragma unroll
        for (int f = 0; f < 4; ++f)
          acc[g][f] = __builtin_amdgcn_mfma_f32_16x16x32_bf16(Af[g], Bf[f], acc[g][f], 0, 0, 0);
    }
  }

  // bias + relu -> l1f (32-row frag-major in LDS)
#pragma unroll
  for (int g = 0; g < 2; ++g)
#pragma unroll
    for (int f = 0; f < 4; ++f) {
      const int col = cg * 64 + f * 16 + cl;
      const float b1 = upd_b1[col];
#pragma unroll
      for (int r = 0; r < 4; ++r) {
        float v = fmaxf(acc[g][f][r] + b1, 0.f);
        l1f[((col >> 5) * 2 + g) * 512 + (((col >> 3) & 3) * 16 + g16 * 4 + r) * 8 + (col & 7)] =
            (__bf16)v;
      }
    }
  __syncthreads();

  // layer2
  f32x4 a2[2][4] = {};
  for (int ks = 0; ks < 8; ++ks) {
    bf16x8 Af[2], Bf[4];
#pragma unroll
    for (int g = 0; g < 2; ++g)
      Af[g] = *(const bf16x8*)(l1f + ((ks * 2 + g) * 64 + lane) * 8);
#pragma unroll
    for (int f = 0; f < 4; ++f)
      Bf[f] = *(const bf16x8*)(uw2f + ((ks * 16 + cg * 4 + f) * 64 + lane) * 8);
#pragma unroll
    for (int g = 0; g < 2; ++g)
#pragma unroll
      for (int f = 0; f < 4; ++f)
        a2[g][f] = __builtin_amdgcn_mfma_f32_16x16x32_bf16(Af[g], Bf[f], a2[g][f], 0, 0, 0);
  }

  if (b < 64) {
    float d0[2][4] = {}, d1[2][4] = {};
#pragma unroll
    for (int f = 0; f < 4; ++f) {
      const int col = cg * 64 + f * 16 + cl;
      const float b2 = upd_b2[col];
      const float w0 = lin2_w[col], w1 = lin2_w[256 + col];
#pragma unroll
      for (int g = 0; g < 2; ++g)
#pragma unroll
        for (int r = 0; r < 4; ++r) {
          float hv = fmaxf(a2[g][f][r] + b2, 0.f);
          d0[g][r] += hv * w0;
          d1[g][r] += hv * w1;
        }
    }
#pragma unroll
    for (int mask = 1; mask < 16; mask <<= 1)
#pragma unroll
      for (int g = 0; g < 2; ++g)
#pragma unroll
        for (int r = 0; r < 4; ++r) {
          d0[g][r] += __shfl_xor(d0[g][r], mask);
          d1[g][r] += __shfl_xor(d1[g][r], mask);
        }
    if (cl == 0) {
#pragma unroll
      for (int g = 0; g < 2; ++g)
#pragma unroll
        for (int r = 0; r < 4; ++r) {
          l2p[cg][g * 16 + g16 * 4 + r][0] = d0[g][r];
          l2p[cg][g * 16 + g16 * 4 + r][1] = d1[g][r];
        }
    }
    __syncthreads();
    if (tid < 32) {
      float s0 = l2p[0][tid][0] + l2p[1][tid][0] + l2p[2][tid][0] + l2p[3][tid][0] + lin2_b[0];
      float s1 = l2p[0][tid][1] + l2p[1][tid][1] + l2p[2][tid][1] + l2p[3][tid][1] + lin2_b[1];
      const int row = b * 32 + tid;
      out[row * 2 + 0] = 1.f / (1.f + expf(-s0));
      out[row * 2 + 1] = 1.f / (1.f + expf(-s1));
    }
  } else {
    float* h2u = (float*)(ws + OFF_H2U);
    const int m0 = (b - 64) * 32;
#pragma unroll
    for (int g = 0; g < 2; ++g)
#pragma unroll
      for (int f = 0; f < 4; ++f) {
        const int col = cg * 64 + f * 16 + cl;
        const float b2 = upd_b2[col];
#pragma unroll
        for (int r = 0; r < 4; ++r) {
          const int rl = g * 16 + g16 * 4 + r;
          h2u[(m0 + rl) * 256 + col] = fmaxf(a2[g][f][r] + b2, 0.f);
        }
      }
  }
}

// =====================================================================
// K7a: UAV LSTM gate partials, k-quartered. grid 256 = 64 m x 4 kq.
// =====================================================================
__global__ __launch_bounds__(256) void k7a_gates(char* __restrict__ ws)
{
  const float* h2u  = (const float*)(ws + OFF_H2U);
  const float* wihT = (const float*)(ws + OFF_WIHT);
  float* part = (float*)(ws + OFF_PART);
  const int m = blockIdx.x >> 2, kq = blockIdx.x & 3;
  const int tid = threadIdx.x;
  const int dir = tid >> 7, hc = tid & 127;
  __shared__ float xs[64];
  if (tid < 64) xs[tid] = h2u[m * 256 + kq * 64 + tid];
  __syncthreads();
  f32x4 a4 = {0.f, 0.f, 0.f, 0.f};
  for (int k = 0; k < 64; ++k) {
    float xv = xs[k];
    f32x4 wv4 = *(const f32x4*)(wihT + dir * 131072 + (kq * 64 + k) * 512 + hc * 4);
#pragma unroll
    for (int g = 0; g < 4; ++g) a4[g] += xv * wv4[g];
  }
  *(f32x4*)(part + (m * 4 + kq) * 1024 + dir * 512 + hc * 4) = a4;
}

// =====================================================================
// K7b: combine partials + LSTM nonlinearity + lin2 + sigmoid (64 blocks)
// =====================================================================
__global__ __launch_bounds__(256) void k7b_final(
    const float* __restrict__ uavl_b, const float* __restrict__ lin2_w,
    const float* __restrict__ lin2_b, float* __restrict__ out, char* __restrict__ ws)
{
  const float* part = (const float*)(ws + OFF_PART);
  const int m = blockIdx.x, tid = threadIdx.x;
  const int dir = tid >> 7, hc = tid & 127;
  f32x4 a4 = {0.f, 0.f, 0.f, 0.f};
#pragma unroll
  for (int kq = 0; kq < 4; ++kq) {
    f32x4 p = *(const f32x4*)(part + (m * 4 + kq) * 1024 + dir * 512 + hc * 4);
#pragma unroll
    for (int g = 0; g < 4; ++g) a4[g] += p[g];
  }
  float bb[4];
#pragma unroll
  for (int g = 0; g < 4; ++g) bb[g] = uavl_b[dir * 512 + g * 128 + hc];
  __shared__ float uo[256];
  float ii = sigm(a4[0] + bb[0]);
  float gg = tanhf(a4[2] + bb[2]);
  float oo = sigm(a4[3] + bb[3]);
  float cc = ii * gg;
  uo[dir * 128 + hc] = oo * tanhf(cc);
  __syncthreads();
  float p0 = uo[tid] * lin2_w[tid];
  float p1 = uo[tid] * lin2_w[256 + tid];
#pragma unroll
  for (int mask = 1; mask < 64; mask <<= 1) {
    p0 += __shfl_xor(p0, mask);
    p1 += __shfl_xor(p1, mask);
  }
  __shared__ float r0s[4], r1s[4];
  const int lane = tid & 63, wv = tid >> 6;
  if (lane == 0) { r0s[wv] = p0; r1s[wv] = p1; }
  __syncthreads();
  if (tid == 0) {
    float d0 = r0s[0] + r0s[1] + r0s[2] + r0s[3] + lin2_b[0];
    float d1 = r1s[0] + r1s[1] + r1s[2] + r1s[3] + lin2_b[1];
    out[(NUQ + m) * 2 + 0] = 1.f / (1.f + expf(-d0));
    out[(NUQ + m) * 2 + 1] = 1.f / (1.f + expf(-d1));
  }
}

// =====================================================================
extern "C" void kernel_launch(void* const* d_in, const int* in_sizes, int n_in,
                              void* d_out, int out_size, void* d_ws, size_t ws_size,
                              hipStream_t stream)
{
  const float* x         = (const float*)d_in[0];
  const float* ul_wih    = (const float*)d_in[3];
  const float* ul_whh    = (const float*)d_in[4];
  const float* ul_b      = (const float*)d_in[5];
  const float* uav_lin_w = (const float*)d_in[6];
  const float* uav_lin_b = (const float*)d_in[7];
  const float* msg_w1    = (const float*)d_in[8];
  const float* msg_b1    = (const float*)d_in[9];
  const float* msg_w2    = (const float*)d_in[10];
  const float* msg_b2    = (const float*)d_in[11];
  const float* wq_w      = (const float*)d_in[12];
  const float* wq_b      = (const float*)d_in[13];
  const float* wr_w      = (const float*)d_in[14];
  const float* wr_b      = (const float*)d_in[15];
  const float* att_w     = (const float*)d_in[16];
  const float* att_b     = (const float*)d_in[17];
  const float* upd_w1    = (const float*)d_in[18];
  const float* upd_b1    = (const float*)d_in[19];
  const float* upd_w2    = (const float*)d_in[20];
  const float* upd_b2    = (const float*)d_in[21];
  const float* uavl_wih  = (const float*)d_in[22];
  const float* uavl_b    = (const float*)d_in[24];
  const float* lin2_w    = (const float*)d_in[25];
  const float* lin2_b    = (const float*)d_in[26];
  char* ws = (char*)d_ws;
  float* out = (float*)d_out;

  k0_prep<<<dim3(161), dim3(256), 0, stream>>>(ul_whh, uavl_wih, msg_w1, msg_w2, upd_w1,
                                               upd_w2, att_w, att_b, wq_w, wq_b, wr_w, wr_b, ws);
  k1_embed<<<dim3(260), dim3(256), 0, stream>>>(x, ul_wih, ul_b, uav_lin_w, uav_lin_b, ws);
  k2_proj<<<dim3(66), dim3(256), 0, stream>>>(msg_b1, ws);
  k3_edge<<<dim3(512), dim3(1024), 0, stream>>>(msg_b2, ws);
  k56_update<<<dim3(66), dim3(256), 0, stream>>>(upd_b1, upd_b2, lin2_w, lin2_b, out, ws);
  k7a_gates<<<dim3(256), dim3(256), 0, stream>>>(ws);
  k7b_final<<<dim3(64), dim3(256), 0, stream>>>(uavl_b, lin2_w, lin2_b, out, ws);
}